// Round 5
// baseline (214.667 us; speedup 1.0000x reference)
//
#include <hip/hip_runtime.h>
#include <hip/hip_bf16.h>

using bf16 = __hip_bfloat16;
typedef short bf16x8 __attribute__((ext_vector_type(8)));
typedef float f32x4 __attribute__((ext_vector_type(4)));

#define CB 2
#define CS 2048
#define CD 1024
#define CH 16
#define CKH 4
#define CHD 64
#define CREP 4
#define CNQ (CH*CHD)    // 1024
#define CNKV (CKH*CHD)  // 256
#define CM (CB*CS)      // 4096

__device__ __forceinline__ unsigned short f2bf(float f) {
  union { float f; unsigned int i; } c; c.f = f;
  unsigned int r = c.i + 0x7FFFu + ((c.i >> 16) & 1u);  // RNE
  return (unsigned short)(r >> 16);
}
__device__ __forceinline__ void gload_lds16(const void* g, void* l) {
  __builtin_amdgcn_global_load_lds(
      (const __attribute__((address_space(1))) void*)g,
      (__attribute__((address_space(3))) void*)l, 16, 0, 0);
}

// ---------------------------------------------------------------------------
// bf16 MFMA GEMM: C[M,N] f32 = A[M,K] bf16 · Bt[N,K]^T bf16.
// 64x128 tile, BK=32, 256 threads = 4 waves (2x2, wave tile 32x64).
// ---------------------------------------------------------------------------
__global__ __launch_bounds__(256) void gemm_mfma_kernel(
    const bf16* __restrict__ A, const bf16* __restrict__ Bt,
    float* __restrict__ C, int Mm, int Nn, int Kk)
{
  __shared__ __align__(16) bf16 As[64 * 32];
  __shared__ __align__(16) bf16 Bs[128 * 32];
  const int tid = threadIdx.x;
  const int lane = tid & 63;
  const int l15 = lane & 15;
  const int g = lane >> 4;
  const int wid = tid >> 6;
  const int wr = (wid >> 1) * 32;
  const int wc = (wid & 1) * 64;
  const int m0 = blockIdx.x * 64;
  const int n0 = blockIdx.y * 128;

  f32x4 acc[2][4];
  #pragma unroll
  for (int i = 0; i < 2; ++i)
    #pragma unroll
    for (int j = 0; j < 4; ++j)
      acc[i][j] = (f32x4){0.f, 0.f, 0.f, 0.f};

  const int sr = tid >> 2;
  const int sc = (tid & 3) * 8;
  const bf16* aSrc = A + (size_t)(m0 + sr) * Kk + sc;
  const bf16* bSrc0 = Bt + (size_t)(n0 + sr) * Kk + sc;
  const bf16* bSrc1 = Bt + (size_t)(n0 + 64 + sr) * Kk + sc;
  bf16* aDstW = &As[(tid & 192) * 8];
  bf16* bDstW = &Bs[(tid & 192) * 8];

  for (int k0 = 0; k0 < Kk; k0 += 32) {
    gload_lds16(aSrc + k0, aDstW);
    gload_lds16(bSrc0 + k0, bDstW);
    gload_lds16(bSrc1 + k0, bDstW + 2048);
    __syncthreads();
    bf16x8 af[2], bfr[4];
    #pragma unroll
    for (int mt = 0; mt < 2; ++mt)
      af[mt] = *(const bf16x8*)&As[(wr + mt * 16 + l15) * 32 + g * 8];
    #pragma unroll
    for (int nt = 0; nt < 4; ++nt)
      bfr[nt] = *(const bf16x8*)&Bs[(wc + nt * 16 + l15) * 32 + g * 8];
    #pragma unroll
    for (int mt = 0; mt < 2; ++mt)
      #pragma unroll
      for (int nt = 0; nt < 4; ++nt)
        acc[mt][nt] = __builtin_amdgcn_mfma_f32_16x16x32_bf16(af[mt], bfr[nt], acc[mt][nt], 0, 0, 0);
    __syncthreads();
  }

  #pragma unroll
  for (int mt = 0; mt < 2; ++mt)
    #pragma unroll
    for (int r4 = 0; r4 < 4; ++r4) {
      const size_t row = (size_t)(m0 + wr + mt * 16 + 4 * g + r4);
      #pragma unroll
      for (int nt = 0; nt < 4; ++nt)
        C[row * Nn + n0 + wc + nt * 16 + l15] = acc[mt][nt][r4];
    }
}

// ---------------------------------------------------------------------------
__global__ void conv_x_kernel(const float* __restrict__ x, bf16* __restrict__ xb)
{
  int i = (blockIdx.x * 256 + threadIdx.x) * 8;
  float4 a = *(const float4*)&x[i];
  float4 b = *(const float4*)&x[i + 4];
  unsigned short* o = (unsigned short*)xb + i;
  *(ushort4*)o = make_ushort4(f2bf(a.x), f2bf(a.y), f2bf(a.z), f2bf(a.w));
  *(ushort4*)(o + 4) = make_ushort4(f2bf(b.x), f2bf(b.y), f2bf(b.z), f2bf(b.w));
}

// W[K][N] f32 -> Wt[N][K] bf16 (LDS-tiled 64x64 transpose + convert).
__global__ __launch_bounds__(256) void transpose_conv_kernel(
    const float* __restrict__ W, bf16* __restrict__ Wt, int Kk, int Nn)
{
  __shared__ float T[64][65];
  const int k0 = blockIdx.x * 64;
  const int n0 = blockIdx.y * 64;
  const int tid = threadIdx.x;
  const int lr = tid >> 4;
  const int lc = (tid & 15) * 4;
  #pragma unroll
  for (int i = 0; i < 4; ++i) {
    float4 v = *(const float4*)&W[(size_t)(k0 + lr + i * 16) * Nn + n0 + lc];
    T[lr + i * 16][lc + 0] = v.x;
    T[lr + i * 16][lc + 1] = v.y;
    T[lr + i * 16][lc + 2] = v.z;
    T[lr + i * 16][lc + 3] = v.w;
  }
  __syncthreads();
  const int rn = tid >> 3;
  const int ck = (tid & 7) * 8;
  #pragma unroll
  for (int i = 0; i < 2; ++i) {
    int nn = rn + i * 32;
    unsigned short u[8];
    #pragma unroll
    for (int e = 0; e < 8; ++e) u[e] = f2bf(T[ck + e][nn]);
    unsigned short* dst = (unsigned short*)Wt + (size_t)(n0 + nn) * Kk + k0 + ck;
    *(ushort4*)dst = make_ushort4(u[0], u[1], u[2], u[3]);
    *(ushort4*)(dst + 4) = make_ushort4(u[4], u[5], u[6], u[7]);
  }
}

// ---------------------------------------------------------------------------
__global__ void rope_q_kernel(const float* __restrict__ qf,
                              const float* __restrict__ fc,
                              const float* __restrict__ fs,
                              bf16* __restrict__ qb)
{
  int p = blockIdx.x * blockDim.x + threadIdx.x;
  int j = p & 31;
  int h = (p >> 5) & 15;
  int s = (p >> 9) & 2047;
  int b = p >> 20;
  const float* src = qf + (size_t)(b * CS + s) * CNQ + h * CHD + j * 2;
  float x0 = src[0], x1 = src[1];
  float c = fc[s * 32 + j], sn = fs[s * 32 + j];
  bf16* dst = qb + ((size_t)(b * CH + h) * CS + s) * CHD + j * 2;
  dst[0] = __float2bfloat16(x0 * c - x1 * sn);
  dst[1] = __float2bfloat16(x0 * sn + x1 * c);
}

__global__ void rope_k_kernel(const float* __restrict__ kvf,
                              const float* __restrict__ fc,
                              const float* __restrict__ fs,
                              bf16* __restrict__ kb)
{
  int p = blockIdx.x * blockDim.x + threadIdx.x;
  int j = p & 31;
  int kh = (p >> 5) & 3;
  int s = (p >> 7) & 2047;
  int b = p >> 18;
  const float* src = kvf + (size_t)(b * CS + s) * 512 + kh * CHD + j * 2;
  float x0 = src[0], x1 = src[1];
  float c = fc[s * 32 + j], sn = fs[s * 32 + j];
  bf16* dst = kb + ((size_t)(b * CKH + kh) * CS + s) * CHD + j * 2;
  dst[0] = __float2bfloat16(x0 * c - x1 * sn);
  dst[1] = __float2bfloat16(x0 * sn + x1 * c);
}

// V transpose: kv_f [B*S][512] (v at cols 256..511) -> vt [B,KH,HD,S] bf16.
__global__ __launch_bounds__(256) void transpose_v_kernel(
    const float* __restrict__ kvf, bf16* __restrict__ vt)
{
  __shared__ float T[64][65];
  const int blk = blockIdx.x;
  const int st = blk & 31;
  const int kh = (blk >> 5) & 3;
  const int b = blk >> 7;
  const int tid = threadIdx.x;
  const int s = tid >> 2;
  const int d0 = (tid & 3) * 16;
  const float* src = kvf + ((size_t)(b * CS + st * 64 + s)) * 512 + 256 + kh * CHD + d0;
  #pragma unroll
  for (int i = 0; i < 4; ++i) {
    float4 v = *(const float4*)(src + i * 4);
    T[s][d0 + i * 4 + 0] = v.x;
    T[s][d0 + i * 4 + 1] = v.y;
    T[s][d0 + i * 4 + 2] = v.z;
    T[s][d0 + i * 4 + 3] = v.w;
  }
  __syncthreads();
  const int d = tid >> 2;
  const int s0 = (tid & 3) * 16;
  unsigned short* dst = (unsigned short*)vt +
      ((size_t)((b * CKH + kh) * CHD + d)) * CS + st * 64 + s0;
  #pragma unroll
  for (int i = 0; i < 2; ++i) {
    unsigned short u[8];
    #pragma unroll
    for (int e = 0; e < 8; ++e) u[e] = f2bf(T[s0 + i * 8 + e][d]);
    *(ushort4*)(dst + i * 8 + 0) = make_ushort4(u[0], u[1], u[2], u[3]);
    *(ushort4*)(dst + i * 8 + 4) = make_ushort4(u[4], u[5], u[6], u[7]);
  }
}

// ---------------------------------------------------------------------------
// MFMA flash attention v4: in-block split-KV x2 + defer-max + exp2 domain +
// psum-via-MFMA. Block = 4 waves = 2 heads x 2 KV-chunks; grid = B*KH*2*64.
// Chunk0: tiles [0,hc) (never masked); chunk1: [hc,qt+1) (owns diagonal).
// Merge at end via LDS (2 barriers). Zero shfls in the common path.
// ---------------------------------------------------------------------------
__global__ __launch_bounds__(256) void flash_mfma_kernel(
    const bf16* __restrict__ qb, const bf16* __restrict__ kb,
    const bf16* __restrict__ vt, bf16* __restrict__ ob)
{
  __shared__ __align__(16) char arena[16896];  // PL(10240) ∪ EX(16384+512)
  auto PL = reinterpret_cast<unsigned short(*)[32][40]>(arena);
  float* EXo = (float*)arena;                  // [2 heads][32 q][64 d]
  float2* EXml = (float2*)(arena + 16384);     // [2 heads][32 q]

  const int tid = threadIdx.x;
  const int lane = tid & 63;
  const int wid = tid >> 6;          // 0..3
  const int hw = wid & 1;            // head within pair
  const int chunk = wid >> 1;        // KV chunk
  const int l15 = lane & 15;
  const int g = lane >> 4;
  const int blk = blockIdx.x;
  const int qt = 63 - (blk & 63);    // longest-first
  const int hp = (blk >> 6) & 1;
  const int kh = (blk >> 7) & 3;
  const int b = blk >> 9;
  const int h = kh * CREP + hp * 2 + hw;
  const int nt = qt + 1;
  const int hc = nt >> 1;
  const int tbeg = chunk ? hc : 0;
  const int tend = chunk ? nt : hc;

  const float SC = 0.18033688f;      // 0.125 * log2(e): exp2 domain

  const bf16* qbase = qb + ((size_t)(b * CH + h) * CS + qt * 32) * CHD;
  const bf16* kbase = kb + (size_t)(b * CKH + kh) * CS * CHD;
  const bf16* vbase = vt + (size_t)(b * CKH + kh) * CHD * CS;  // [d][s]

  bf16x8 qf[2][2];
  #pragma unroll
  for (int qs = 0; qs < 2; ++qs)
    #pragma unroll
    for (int c = 0; c < 2; ++c)
      qf[qs][c] = *(const bf16x8*)(qbase + (qs * 16 + l15) * CHD + c * 32 + g * 8);

  bf16x8 ones;
  #pragma unroll
  for (int e = 0; e < 8; ++e) ones[e] = (short)0x3F80;  // bf16 1.0

  f32x4 oacc[2][4];
  f32x4 lacc[2];
  #pragma unroll
  for (int qs = 0; qs < 2; ++qs) {
    lacc[qs] = (f32x4){0.f, 0.f, 0.f, 0.f};
    #pragma unroll
    for (int dt = 0; dt < 4; ++dt)
      oacc[qs][dt] = (f32x4){0.f, 0.f, 0.f, 0.f};
  }
  float mrow[2] = {-1e30f, -1e30f};

  for (int t = tbeg; t < tend; ++t) {
    // K and V^T fragments straight from global (L2-resident)
    bf16x8 kf[2][2], vfr[4];
    #pragma unroll
    for (int kt = 0; kt < 2; ++kt)
      #pragma unroll
      for (int c = 0; c < 2; ++c)
        kf[kt][c] = *(const bf16x8*)(kbase + (size_t)(t * 32 + kt * 16 + l15) * CHD + c * 32 + g * 8);
    #pragma unroll
    for (int dt = 0; dt < 4; ++dt)
      vfr[dt] = *(const bf16x8*)&vbase[(size_t)(dt * 16 + l15) * CS + t * 32 + g * 8];

    // QK^T (swapped): S^T, col=q, rows=k
    f32x4 sacc[2][2];
    #pragma unroll
    for (int kt = 0; kt < 2; ++kt)
      #pragma unroll
      for (int qs = 0; qs < 2; ++qs)
        sacc[kt][qs] = (f32x4){0.f, 0.f, 0.f, 0.f};
    #pragma unroll
    for (int c = 0; c < 2; ++c)
      #pragma unroll
      for (int kt = 0; kt < 2; ++kt)
        #pragma unroll
        for (int qs = 0; qs < 2; ++qs)
          sacc[kt][qs] = __builtin_amdgcn_mfma_f32_16x16x32_bf16(kf[kt][c], qf[qs][c], sacc[kt][qs], 0, 0, 0);

    // softmax, defer-max common path (no cross-lane ops)
    #pragma unroll
    for (int qs = 0; qs < 2; ++qs) {
      float e[8];
      float pm = -1e30f;
      #pragma unroll
      for (int kt = 0; kt < 2; ++kt)
        #pragma unroll
        for (int r = 0; r < 4; ++r) {
          float v = sacc[kt][qs][r] * SC;
          if (t == qt) {                       // diagonal tile (chunk1 only)
            int koff = kt * 16 + 4 * g + r;
            if (koff > qs * 16 + l15) v = -1e30f;
          }
          e[kt * 4 + r] = v;
          pm = fmaxf(pm, v);
        }
      if (__any(pm > mrow[qs] + 8.0f)) {       // slow path: exact rescale
        pm = fmaxf(pm, __shfl_xor(pm, 16, 64));
        pm = fmaxf(pm, __shfl_xor(pm, 32, 64));
        float nm = fmaxf(mrow[qs], pm);
        float corr = exp2f(mrow[qs] - nm);
        mrow[qs] = nm;
        lacc[qs] *= corr;
        #pragma unroll
        for (int dt = 0; dt < 4; ++dt) oacc[qs][dt] *= corr;
      }
      unsigned short pb[8];
      #pragma unroll
      for (int i = 0; i < 8; ++i)
        pb[i] = f2bf(exp2f(e[i] - mrow[qs]));  // p <= 2^8
      #pragma unroll
      for (int kt = 0; kt < 2; ++kt)
        *(ushort4*)&PL[wid][qs * 16 + l15][kt * 16 + 4 * g] =
            make_ushort4(pb[kt * 4 + 0], pb[kt * 4 + 1], pb[kt * 4 + 2], pb[kt * 4 + 3]);
    }
    // PV + psum (same-wave LDS RAW; compiler inserts lgkmcnt wait)
    #pragma unroll
    for (int qs = 0; qs < 2; ++qs) {
      bf16x8 pf = *(const bf16x8*)&PL[wid][qs * 16 + l15][g * 8];
      lacc[qs] = __builtin_amdgcn_mfma_f32_16x16x32_bf16(ones, pf, lacc[qs], 0, 0, 0);
      #pragma unroll
      for (int dt = 0; dt < 4; ++dt)
        oacc[qs][dt] = __builtin_amdgcn_mfma_f32_16x16x32_bf16(vfr[dt], pf, oacc[qs][dt], 0, 0, 0);
    }
  }

  // merge chunks via LDS (arena reused after barrier)
  __syncthreads();
  if (chunk == 1) {
    #pragma unroll
    for (int qs = 0; qs < 2; ++qs) {
      int q = qs * 16 + l15;
      #pragma unroll
      for (int dt = 0; dt < 4; ++dt)
        *(float4*)&EXo[(size_t)(hw * 32 + q) * 64 + dt * 16 + 4 * g] =
            make_float4(oacc[qs][dt][0], oacc[qs][dt][1], oacc[qs][dt][2], oacc[qs][dt][3]);
      if (g == 0)
        EXml[hw * 32 + q] = make_float2(mrow[qs], lacc[qs][0]);
    }
  }
  __syncthreads();
  if (chunk == 0) {
    #pragma unroll
    for (int qs = 0; qs < 2; ++qs) {
      int q = qs * 16 + l15;
      float2 ml1 = EXml[hw * 32 + q];
      float m0 = mrow[qs], l0 = lacc[qs][0];
      float M = fmaxf(m0, ml1.x);
      float c0 = exp2f(m0 - M), c1 = exp2f(ml1.x - M);
      float inv = 1.0f / (c0 * l0 + c1 * ml1.y);
      unsigned short* orow = (unsigned short*)ob + (size_t)(b * CS + qt * 32 + q) * CNQ + h * CHD;
      #pragma unroll
      for (int dt = 0; dt < 4; ++dt) {
        float4 o1 = *(const float4*)&EXo[(size_t)(hw * 32 + q) * 64 + dt * 16 + 4 * g];
        *(ushort4*)&orow[dt * 16 + 4 * g] = make_ushort4(
            f2bf((c0 * oacc[qs][dt][0] + c1 * o1.x) * inv),
            f2bf((c0 * oacc[qs][dt][1] + c1 * o1.y) * inv),
            f2bf((c0 * oacc[qs][dt][2] + c1 * o1.z) * inv),
            f2bf((c0 * oacc[qs][dt][3] + c1 * o1.w) * inv));
      }
    }
  }
}

// ---------------------------------------------------------------------------
extern "C" void kernel_launch(void* const* d_in, const int* in_sizes, int n_in,
                              void* d_out, int out_size, void* d_ws, size_t ws_size,
                              hipStream_t stream)
{
  const float* x  = (const float*)d_in[0];
  const float* wq = (const float*)d_in[1];
  const float* wk = (const float*)d_in[2];
  const float* wv = (const float*)d_in[3];
  const float* wo = (const float*)d_in[4];
  const float* fc = (const float*)d_in[5];
  const float* fs = (const float*)d_in[6];
  float* out = (float*)d_out;

  char* ws = (char*)d_ws;
  bf16*  x_b  = (bf16*)(ws);                 // [0,8M)
  float* q_f  = (float*)(ws + 8388608);      // [8M,16M)
  float* kv_f = (float*)(ws + 25165824);     // [24M,32M) fused k|v
  bf16*  wqt  = (bf16*)(ws + 33554432);      // 2MB
  bf16*  wkvt = (bf16*)(ws + 35651584);      // 1MB
  bf16*  q_b  = (bf16*)(ws);                 // reuse x_b
  bf16*  k_b  = (bf16*)(ws + 8388608);       // reuse q_f
  bf16*  v_t  = (bf16*)(ws + 10485760);      // 2MB, V^T [B,KH,HD,S]
  bf16*  o_b  = (bf16*)(ws + 12582912);      // 8MB
  bf16*  wot  = (bf16*)(ws + 25165824);      // reuse kv_f

  conv_x_kernel<<<2048, 256, 0, stream>>>(x, x_b);
  transpose_conv_kernel<<<dim3(16, 16), 256, 0, stream>>>(wq, wqt, CD, CNQ);
  transpose_conv_kernel<<<dim3(16, 4), 256, 0, stream>>>(wk, wkvt, CD, CNKV);
  transpose_conv_kernel<<<dim3(16, 4), 256, 0, stream>>>(wv, wkvt + 256 * CD, CD, CNKV);
  gemm_mfma_kernel<<<dim3(64, 8), 256, 0, stream>>>(x_b, wqt, q_f, CM, CNQ, CD);
  gemm_mfma_kernel<<<dim3(64, 4), 256, 0, stream>>>(x_b, wkvt, kv_f, CM, 512, CD);
  rope_q_kernel<<<(CB * CS * CH * 32) / 256, 256, 0, stream>>>(q_f, fc, fs, q_b);
  rope_k_kernel<<<(CB * CS * CKH * 32) / 256, 256, 0, stream>>>(kv_f, fc, fs, k_b);
  transpose_v_kernel<<<CB * CKH * 32, 256, 0, stream>>>(kv_f, v_t);
  transpose_conv_kernel<<<dim3(16, 16), 256, 0, stream>>>(wo, wot, CNQ, CD);
  flash_mfma_kernel<<<CB * CKH * 2 * 64, 256, 0, stream>>>(q_b, k_b, v_t, o_b);
  gemm_mfma_kernel<<<dim3(64, 8), 256, 0, stream>>>(o_b, wot, out, CM, CD, CNQ);
}

// Round 6
// 152.040 us; speedup vs baseline: 1.4119x; 1.4119x over previous
//
#include <hip/hip_runtime.h>
#include <hip/hip_bf16.h>

using bf16 = __hip_bfloat16;
typedef short bf16x8 __attribute__((ext_vector_type(8)));
typedef float f32x4 __attribute__((ext_vector_type(4)));

#define CB 2
#define CS 2048
#define CD 1024
#define CH 16
#define CKH 4
#define CHD 64
#define CREP 4
#define CNQ (CH*CHD)    // 1024
#define CNKV (CKH*CHD)  // 256
#define CM (CB*CS)      // 4096

__device__ __forceinline__ unsigned short f2bf(float f) {
  union { float f; unsigned int i; } c; c.f = f;
  unsigned int r = c.i + 0x7FFFu + ((c.i >> 16) & 1u);  // RNE
  return (unsigned short)(r >> 16);
}
__device__ __forceinline__ void gload_lds16(const void* g, void* l) {
  __builtin_amdgcn_global_load_lds(
      (const __attribute__((address_space(1))) void*)g,
      (__attribute__((address_space(3))) void*)l, 16, 0, 0);
}

// ---------------------------------------------------------------------------
// bf16 MFMA GEMM: C[M,N] f32 = A[M,K] bf16 · Bt[N,K]^T bf16. (unchanged)
// ---------------------------------------------------------------------------
__global__ __launch_bounds__(256) void gemm_mfma_kernel(
    const bf16* __restrict__ A, const bf16* __restrict__ Bt,
    float* __restrict__ C, int Mm, int Nn, int Kk)
{
  __shared__ __align__(16) bf16 As[64 * 32];
  __shared__ __align__(16) bf16 Bs[128 * 32];
  const int tid = threadIdx.x;
  const int lane = tid & 63;
  const int l15 = lane & 15;
  const int g = lane >> 4;
  const int wid = tid >> 6;
  const int wr = (wid >> 1) * 32;
  const int wc = (wid & 1) * 64;
  const int m0 = blockIdx.x * 64;
  const int n0 = blockIdx.y * 128;

  f32x4 acc[2][4];
  #pragma unroll
  for (int i = 0; i < 2; ++i)
    #pragma unroll
    for (int j = 0; j < 4; ++j)
      acc[i][j] = (f32x4){0.f, 0.f, 0.f, 0.f};

  const int sr = tid >> 2;
  const int sc = (tid & 3) * 8;
  const bf16* aSrc = A + (size_t)(m0 + sr) * Kk + sc;
  const bf16* bSrc0 = Bt + (size_t)(n0 + sr) * Kk + sc;
  const bf16* bSrc1 = Bt + (size_t)(n0 + 64 + sr) * Kk + sc;
  bf16* aDstW = &As[(tid & 192) * 8];
  bf16* bDstW = &Bs[(tid & 192) * 8];

  for (int k0 = 0; k0 < Kk; k0 += 32) {
    gload_lds16(aSrc + k0, aDstW);
    gload_lds16(bSrc0 + k0, bDstW);
    gload_lds16(bSrc1 + k0, bDstW + 2048);
    __syncthreads();
    bf16x8 af[2], bfr[4];
    #pragma unroll
    for (int mt = 0; mt < 2; ++mt)
      af[mt] = *(const bf16x8*)&As[(wr + mt * 16 + l15) * 32 + g * 8];
    #pragma unroll
    for (int nt = 0; nt < 4; ++nt)
      bfr[nt] = *(const bf16x8*)&Bs[(wc + nt * 16 + l15) * 32 + g * 8];
    #pragma unroll
    for (int mt = 0; mt < 2; ++mt)
      #pragma unroll
      for (int nt = 0; nt < 4; ++nt)
        acc[mt][nt] = __builtin_amdgcn_mfma_f32_16x16x32_bf16(af[mt], bfr[nt], acc[mt][nt], 0, 0, 0);
    __syncthreads();
  }

  #pragma unroll
  for (int mt = 0; mt < 2; ++mt)
    #pragma unroll
    for (int r4 = 0; r4 < 4; ++r4) {
      const size_t row = (size_t)(m0 + wr + mt * 16 + 4 * g + r4);
      #pragma unroll
      for (int nt = 0; nt < 4; ++nt)
        C[row * Nn + n0 + wc + nt * 16 + l15] = acc[mt][nt][r4];
    }
}

// ---------------------------------------------------------------------------
__global__ void conv_x_kernel(const float* __restrict__ x, bf16* __restrict__ xb)
{
  int i = (blockIdx.x * 256 + threadIdx.x) * 8;
  float4 a = *(const float4*)&x[i];
  float4 b = *(const float4*)&x[i + 4];
  unsigned short* o = (unsigned short*)xb + i;
  *(ushort4*)o = make_ushort4(f2bf(a.x), f2bf(a.y), f2bf(a.z), f2bf(a.w));
  *(ushort4*)(o + 4) = make_ushort4(f2bf(b.x), f2bf(b.y), f2bf(b.z), f2bf(b.w));
}

// W[K][N] f32 -> Wt[N][K] bf16 (LDS-tiled 64x64 transpose + convert).
__global__ __launch_bounds__(256) void transpose_conv_kernel(
    const float* __restrict__ W, bf16* __restrict__ Wt, int Kk, int Nn)
{
  __shared__ float T[64][65];
  const int k0 = blockIdx.x * 64;
  const int n0 = blockIdx.y * 64;
  const int tid = threadIdx.x;
  const int lr = tid >> 4;
  const int lc = (tid & 15) * 4;
  #pragma unroll
  for (int i = 0; i < 4; ++i) {
    float4 v = *(const float4*)&W[(size_t)(k0 + lr + i * 16) * Nn + n0 + lc];
    T[lr + i * 16][lc + 0] = v.x;
    T[lr + i * 16][lc + 1] = v.y;
    T[lr + i * 16][lc + 2] = v.z;
    T[lr + i * 16][lc + 3] = v.w;
  }
  __syncthreads();
  const int rn = tid >> 3;
  const int ck = (tid & 7) * 8;
  #pragma unroll
  for (int i = 0; i < 2; ++i) {
    int nn = rn + i * 32;
    unsigned short u[8];
    #pragma unroll
    for (int e = 0; e < 8; ++e) u[e] = f2bf(T[ck + e][nn]);
    unsigned short* dst = (unsigned short*)Wt + (size_t)(n0 + nn) * Kk + k0 + ck;
    *(ushort4*)dst = make_ushort4(u[0], u[1], u[2], u[3]);
    *(ushort4*)(dst + 4) = make_ushort4(u[4], u[5], u[6], u[7]);
  }
}

// ---------------------------------------------------------------------------
__global__ void rope_q_kernel(const float* __restrict__ qf,
                              const float* __restrict__ fc,
                              const float* __restrict__ fs,
                              bf16* __restrict__ qb)
{
  int p = blockIdx.x * blockDim.x + threadIdx.x;
  int j = p & 31;
  int h = (p >> 5) & 15;
  int s = (p >> 9) & 2047;
  int b = p >> 20;
  const float* src = qf + (size_t)(b * CS + s) * CNQ + h * CHD + j * 2;
  float x0 = src[0], x1 = src[1];
  float c = fc[s * 32 + j], sn = fs[s * 32 + j];
  bf16* dst = qb + ((size_t)(b * CH + h) * CS + s) * CHD + j * 2;
  dst[0] = __float2bfloat16(x0 * c - x1 * sn);
  dst[1] = __float2bfloat16(x0 * sn + x1 * c);
}

__global__ void rope_k_kernel(const float* __restrict__ kvf,
                              const float* __restrict__ fc,
                              const float* __restrict__ fs,
                              bf16* __restrict__ kb)
{
  int p = blockIdx.x * blockDim.x + threadIdx.x;
  int j = p & 31;
  int kh = (p >> 5) & 3;
  int s = (p >> 7) & 2047;
  int b = p >> 18;
  const float* src = kvf + (size_t)(b * CS + s) * 512 + kh * CHD + j * 2;
  float x0 = src[0], x1 = src[1];
  float c = fc[s * 32 + j], sn = fs[s * 32 + j];
  bf16* dst = kb + ((size_t)(b * CKH + kh) * CS + s) * CHD + j * 2;
  dst[0] = __float2bfloat16(x0 * c - x1 * sn);
  dst[1] = __float2bfloat16(x0 * sn + x1 * c);
}

// V transpose: kv_f [B*S][512] (v at cols 256..511) -> vt [B,KH,HD,S] bf16.
__global__ __launch_bounds__(256) void transpose_v_kernel(
    const float* __restrict__ kvf, bf16* __restrict__ vt)
{
  __shared__ float T[64][65];
  const int blk = blockIdx.x;
  const int st = blk & 31;
  const int kh = (blk >> 5) & 3;
  const int b = blk >> 7;
  const int tid = threadIdx.x;
  const int s = tid >> 2;
  const int d0 = (tid & 3) * 16;
  const float* src = kvf + ((size_t)(b * CS + st * 64 + s)) * 512 + 256 + kh * CHD + d0;
  #pragma unroll
  for (int i = 0; i < 4; ++i) {
    float4 v = *(const float4*)(src + i * 4);
    T[s][d0 + i * 4 + 0] = v.x;
    T[s][d0 + i * 4 + 1] = v.y;
    T[s][d0 + i * 4 + 2] = v.z;
    T[s][d0 + i * 4 + 3] = v.w;
  }
  __syncthreads();
  const int d = tid >> 2;
  const int s0 = (tid & 3) * 16;
  unsigned short* dst = (unsigned short*)vt +
      ((size_t)((b * CKH + kh) * CHD + d)) * CS + st * 64 + s0;
  #pragma unroll
  for (int i = 0; i < 2; ++i) {
    unsigned short u[8];
    #pragma unroll
    for (int e = 0; e < 8; ++e) u[e] = f2bf(T[s0 + i * 8 + e][d]);
    *(ushort4*)(dst + i * 8 + 0) = make_ushort4(u[0], u[1], u[2], u[3]);
    *(ushort4*)(dst + i * 8 + 4) = make_ushort4(u[4], u[5], u[6], u[7]);
  }
}

// ---------------------------------------------------------------------------
// MFMA flash attention v5: block-level LDS staging of K and V^T via
// global_load_lds (coalesced), double-buffered, counted vmcnt + raw barriers.
// Block = 4 waves = 4 q-heads of one kv group, one 32-row q-tile, KVBLK=64.
// LDS chunk XOR-swizzle (chunk ^= row&7) via pre-swizzled global source;
// ds_read_b128 fragments land uniform 8 lanes/bank-group (b128 optimum).
// Grid = 512, blk%8 = (b*4+kh) -> one (b,kh) per XCD (K/V L2-local); qt
// descending for LPT.
// ---------------------------------------------------------------------------
__global__ __launch_bounds__(256, 2) void flash_mfma_kernel(
    const bf16* __restrict__ qb, const bf16* __restrict__ kb,
    const bf16* __restrict__ vt, bf16* __restrict__ ob)
{
  __shared__ __align__(16) char arena[51200];
  char* KL = arena;                       // [2][8192]: K tile 64x(64 bf16)
  char* VL = arena + 16384;               // [2][8192]: V^T tile 64x(64 bf16)
  const int tid = threadIdx.x;
  const int lane = tid & 63;
  const int wid = tid >> 6;
  unsigned short* PLW = (unsigned short*)(arena + 32768) + wid * 2304; // [32][72]
  const int l15 = lane & 15;
  const int g = lane >> 4;
  const int blk = blockIdx.x;
  const int grp = blk & 7;                // b*4+kh
  const int qt = 63 - (blk >> 3);         // LPT
  const int kh = grp & 3;
  const int b = grp >> 2;
  const int h = kh * CREP + wid;
  const int N64 = (qt >> 1) + 1;
  const float SC = 0.18033688f;           // 0.125 * log2(e)

  const bf16* qbase = qb + ((size_t)(b * CH + h) * CS + qt * 32) * CHD;
  const bf16* kbase = kb + (size_t)(b * CKH + kh) * CS * CHD;
  const bf16* vbase = vt + (size_t)(b * CKH + kh) * CHD * CS;  // [d][s]

  // Q fragments (once per kernel)
  bf16x8 qf[2][2];
  #pragma unroll
  for (int qs = 0; qs < 2; ++qs)
    #pragma unroll
    for (int c = 0; c < 2; ++c)
      qf[qs][c] = *(const bf16x8*)(qbase + (qs * 16 + l15) * CHD + c * 32 + g * 8);

  bf16x8 ones;
  #pragma unroll
  for (int e = 0; e < 8; ++e) ones[e] = (short)0x3F80;  // bf16 1.0

  f32x4 oacc[2][4];
  f32x4 lacc[2];
  #pragma unroll
  for (int qs = 0; qs < 2; ++qs) {
    lacc[qs] = (f32x4){0.f, 0.f, 0.f, 0.f};
    #pragma unroll
    for (int dt = 0; dt < 4; ++dt)
      oacc[qs][dt] = (f32x4){0.f, 0.f, 0.f, 0.f};
  }
  float mrow[2] = {-1e30f, -1e30f};

  // staging coords: thread t -> row slr (0..31), LDS chunk t&7 holds global
  // chunk scg = (t&7)^(slr&7)  (inverse-swizzled source, rule #21)
  const int slr = tid >> 3;
  const int scg = (tid & 7) ^ (slr & 7);
  const bf16* kstage = kbase + (size_t)slr * CHD + scg * 8;
  const bf16* vstage = vbase + (size_t)slr * CS + scg * 8;
  char* kdst = KL + wid * 1024;           // wave-uniform base (+lane*16 by HW)
  char* vdst = VL + wid * 1024;

#define STAGE(bi, t64) do {                                        \
    const bf16* ks_ = kstage + (size_t)(t64) * 64 * CHD;           \
    const bf16* vs_ = vstage + (t64) * 64;                         \
    gload_lds16(ks_,            kdst + (bi) * 8192);               \
    gload_lds16(ks_ + 32 * CHD, kdst + (bi) * 8192 + 4096);        \
    gload_lds16(vs_,            vdst + (bi) * 8192);               \
    gload_lds16(vs_ + 32 * CS,  vdst + (bi) * 8192 + 4096);        \
  } while (0)

  int bi = 0;
  STAGE(0, 0);
  for (int t = 0; t < N64; ++t) {
    if (t + 1 < N64) {
      STAGE(bi ^ 1, t + 1);
      asm volatile("s_waitcnt vmcnt(4)" ::: "memory");  // tile-t loads done
    } else {
      asm volatile("s_waitcnt vmcnt(0)" ::: "memory");
    }
    __builtin_amdgcn_s_barrier();
    asm volatile("" ::: "memory");

    const char* KB = KL + bi * 8192;
    const char* VB = VL + bi * 8192;
    bf16x8 kfr[4][2], vfr[4][2];
    #pragma unroll
    for (int kt = 0; kt < 4; ++kt) {
      int row = kt * 16 + l15;
      #pragma unroll
      for (int c = 0; c < 2; ++c)
        kfr[kt][c] = *(const bf16x8*)(KB + row * 128 + (((c * 4 + g) ^ (row & 7)) << 4));
    }
    #pragma unroll
    for (int dt = 0; dt < 4; ++dt) {
      int row = dt * 16 + l15;
      #pragma unroll
      for (int st = 0; st < 2; ++st)
        vfr[dt][st] = *(const bf16x8*)(VB + row * 128 + (((st * 4 + g) ^ (row & 7)) << 4));
    }

    // QK^T (swapped): S^T[k][q], 64 k-rows x 32 q
    f32x4 sacc[4][2];
    #pragma unroll
    for (int kt = 0; kt < 4; ++kt)
      #pragma unroll
      for (int qs = 0; qs < 2; ++qs)
        sacc[kt][qs] = (f32x4){0.f, 0.f, 0.f, 0.f};
    #pragma unroll
    for (int c = 0; c < 2; ++c)
      #pragma unroll
      for (int kt = 0; kt < 4; ++kt)
        #pragma unroll
        for (int qs = 0; qs < 2; ++qs)
          sacc[kt][qs] = __builtin_amdgcn_mfma_f32_16x16x32_bf16(kfr[kt][c], qf[qs][c], sacc[kt][qs], 0, 0, 0);

    const bool diag = (t == N64 - 1);
    #pragma unroll
    for (int qs = 0; qs < 2; ++qs) {
      float e[16];
      float pm = -1e30f;
      #pragma unroll
      for (int kt = 0; kt < 4; ++kt)
        #pragma unroll
        for (int r = 0; r < 4; ++r) {
          float v = sacc[kt][qs][r] * SC;
          if (diag) {
            int koff = t * 64 + kt * 16 + 4 * g + r;
            if (koff > qt * 32 + qs * 16 + l15) v = -1e30f;
          }
          e[kt * 4 + r] = v;
          pm = fmaxf(pm, v);
        }
      if (__any(pm > mrow[qs] + 8.0f)) {       // slow path: exact rescale
        pm = fmaxf(pm, __shfl_xor(pm, 16, 64));
        pm = fmaxf(pm, __shfl_xor(pm, 32, 64));
        float nm = fmaxf(mrow[qs], pm);
        float corr = exp2f(mrow[qs] - nm);
        mrow[qs] = nm;
        lacc[qs] *= corr;
        #pragma unroll
        for (int dt = 0; dt < 4; ++dt) oacc[qs][dt] *= corr;
      }
      unsigned short pb[16];
      #pragma unroll
      for (int i = 0; i < 16; ++i)
        pb[i] = f2bf(exp2f(e[i] - mrow[qs]));  // p <= 2^8
      #pragma unroll
      for (int kt = 0; kt < 4; ++kt)
        *(ushort4*)&PLW[(qs * 16 + l15) * 72 + kt * 16 + 4 * g] =
            make_ushort4(pb[kt * 4 + 0], pb[kt * 4 + 1], pb[kt * 4 + 2], pb[kt * 4 + 3]);
    }

    // PV + psum (same-wave LDS RAW; compiler inserts lgkmcnt waits)
    #pragma unroll
    for (int qs = 0; qs < 2; ++qs) {
      #pragma unroll
      for (int st = 0; st < 2; ++st) {
        bf16x8 pf = *(const bf16x8*)&PLW[(qs * 16 + l15) * 72 + st * 32 + g * 8];
        lacc[qs] = __builtin_amdgcn_mfma_f32_16x16x32_bf16(ones, pf, lacc[qs], 0, 0, 0);
        #pragma unroll
        for (int dt = 0; dt < 4; ++dt)
          oacc[qs][dt] = __builtin_amdgcn_mfma_f32_16x16x32_bf16(vfr[dt][st], pf, oacc[qs][dt], 0, 0, 0);
      }
    }

    asm volatile("" ::: "memory");
    __builtin_amdgcn_s_barrier();            // all reads of buf bi done
    bi ^= 1;
  }
#undef STAGE

  #pragma unroll
  for (int qs = 0; qs < 2; ++qs) {
    float inv = 1.0f / lacc[qs][0];
    int qg = qt * 32 + qs * 16 + l15;
    unsigned short* orow = (unsigned short*)ob + (size_t)(b * CS + qg) * CNQ + h * CHD;
    #pragma unroll
    for (int dt = 0; dt < 4; ++dt) {
      *(ushort4*)&orow[dt * 16 + 4 * g] =
          make_ushort4(f2bf(oacc[qs][dt][0] * inv), f2bf(oacc[qs][dt][1] * inv),
                       f2bf(oacc[qs][dt][2] * inv), f2bf(oacc[qs][dt][3] * inv));
    }
  }
}

// ---------------------------------------------------------------------------
extern "C" void kernel_launch(void* const* d_in, const int* in_sizes, int n_in,
                              void* d_out, int out_size, void* d_ws, size_t ws_size,
                              hipStream_t stream)
{
  const float* x  = (const float*)d_in[0];
  const float* wq = (const float*)d_in[1];
  const float* wk = (const float*)d_in[2];
  const float* wv = (const float*)d_in[3];
  const float* wo = (const float*)d_in[4];
  const float* fc = (const float*)d_in[5];
  const float* fs = (const float*)d_in[6];
  float* out = (float*)d_out;

  char* ws = (char*)d_ws;
  bf16*  x_b  = (bf16*)(ws);                 // [0,8M)
  float* q_f  = (float*)(ws + 8388608);      // [8M,16M)
  float* kv_f = (float*)(ws + 25165824);     // [24M,32M) fused k|v
  bf16*  wqt  = (bf16*)(ws + 33554432);      // 2MB
  bf16*  wkvt = (bf16*)(ws + 35651584);      // 1MB
  bf16*  q_b  = (bf16*)(ws);                 // reuse x_b
  bf16*  k_b  = (bf16*)(ws + 8388608);       // reuse q_f
  bf16*  v_t  = (bf16*)(ws + 10485760);      // 2MB, V^T [B,KH,HD,S]
  bf16*  o_b  = (bf16*)(ws + 12582912);      // 8MB
  bf16*  wot  = (bf16*)(ws + 25165824);      // reuse kv_f

  conv_x_kernel<<<2048, 256, 0, stream>>>(x, x_b);
  transpose_conv_kernel<<<dim3(16, 16), 256, 0, stream>>>(wq, wqt, CD, CNQ);
  transpose_conv_kernel<<<dim3(16, 4), 256, 0, stream>>>(wk, wkvt, CD, CNKV);
  transpose_conv_kernel<<<dim3(16, 4), 256, 0, stream>>>(wv, wkvt + 256 * CD, CD, CNKV);
  gemm_mfma_kernel<<<dim3(64, 8), 256, 0, stream>>>(x_b, wqt, q_f, CM, CNQ, CD);
  gemm_mfma_kernel<<<dim3(64, 4), 256, 0, stream>>>(x_b, wkvt, kv_f, CM, 512, CD);
  rope_q_kernel<<<(CB * CS * CH * 32) / 256, 256, 0, stream>>>(q_f, fc, fs, q_b);
  rope_k_kernel<<<(CB * CS * CKH * 32) / 256, 256, 0, stream>>>(kv_f, fc, fs, k_b);
  transpose_v_kernel<<<CB * CKH * 32, 256, 0, stream>>>(kv_f, v_t);
  transpose_conv_kernel<<<dim3(16, 16), 256, 0, stream>>>(wo, wot, CNQ, CD);
  flash_mfma_kernel<<<512, 256, 0, stream>>>(q_b, k_b, v_t, o_b);
  gemm_mfma_kernel<<<dim3(64, 8), 256, 0, stream>>>(o_b, wot, out, CM, CD, CNQ);
}

// Round 8
// 136.369 us; speedup vs baseline: 1.5742x; 1.1149x over previous
//
#include <hip/hip_runtime.h>
#include <hip/hip_bf16.h>

using bf16 = __hip_bfloat16;
typedef short bf16x8 __attribute__((ext_vector_type(8)));
typedef float f32x4 __attribute__((ext_vector_type(4)));

#define CB 2
#define CS 2048
#define CD 1024
#define CH 16
#define CKH 4
#define CHD 64
#define CREP 4
#define CNQ (CH*CHD)    // 1024
#define CNKV (CKH*CHD)  // 256
#define CM (CB*CS)      // 4096

__device__ __forceinline__ unsigned short f2bf(float f) {
  union { float f; unsigned int i; } c; c.f = f;
  unsigned int r = c.i + 0x7FFFu + ((c.i >> 16) & 1u);  // RNE
  return (unsigned short)(r >> 16);
}
__device__ __forceinline__ void gload_lds16(const void* g, void* l) {
  __builtin_amdgcn_global_load_lds(
      (const __attribute__((address_space(1))) void*)g,
      (__attribute__((address_space(3))) void*)l, 16, 0, 0);
}

// ---------------------------------------------------------------------------
// bf16 MFMA GEMM v2: C[M,N] f32 = A[M,K] bf16 (row stride lda) · Bt[N,K]^T.
// 128x128 tile, BK=32, 4 waves (2x2 of 64x64), double-buffered LDS with
// counted vmcnt (R6 flash staging discipline). 16 MFMA : 8 ds_read per
// wave K-step.
// ---------------------------------------------------------------------------
__global__ __launch_bounds__(256) void gemm_mfma_kernel(
    const bf16* __restrict__ A, const bf16* __restrict__ Bt,
    float* __restrict__ C, int Mm, int Nn, int Kk, int lda)
{
  __shared__ __align__(16) bf16 As[2][128 * 32];
  __shared__ __align__(16) bf16 Bs[2][128 * 32];
  const int tid = threadIdx.x;
  const int lane = tid & 63;
  const int l15 = lane & 15;
  const int g = lane >> 4;
  const int wid = tid >> 6;
  const int wr = (wid >> 1) * 64;
  const int wc = (wid & 1) * 64;
  const int m0 = blockIdx.x * 128;
  const int n0 = blockIdx.y * 128;

  f32x4 acc[4][4];
  #pragma unroll
  for (int i = 0; i < 4; ++i)
    #pragma unroll
    for (int j = 0; j < 4; ++j)
      acc[i][j] = (f32x4){0.f, 0.f, 0.f, 0.f};

  const int sr = tid >> 2;            // staging row 0..63
  const int sc = (tid & 3) * 8;       // 16B k-chunk
  const bf16* aSrc = A + (size_t)(m0 + sr) * lda + sc;
  const bf16* bSrc = Bt + (size_t)(n0 + sr) * Kk + sc;
  const int sOff = (tid & 192) * 8;   // wave-uniform linear LDS base (elems)

#define GSTAGE(bi, k0) do {                                             \
    gload_lds16(aSrc + (k0),                     &As[bi][sOff]);        \
    gload_lds16(aSrc + 64 * (size_t)lda + (k0),  &As[bi][sOff + 2048]); \
    gload_lds16(bSrc + (k0),                     &Bs[bi][sOff]);        \
    gload_lds16(bSrc + 64 * (size_t)Kk + (k0),   &Bs[bi][sOff + 2048]); \
  } while (0)

  const int nt = Kk >> 5;
  int bi = 0;
  GSTAGE(0, 0);
  for (int t = 0; t < nt; ++t) {
    if (t + 1 < nt) {
      GSTAGE(bi ^ 1, (t + 1) * 32);
      asm volatile("s_waitcnt vmcnt(4)" ::: "memory");   // tile-t loads done
    } else {
      asm volatile("s_waitcnt vmcnt(0)" ::: "memory");
    }
    __builtin_amdgcn_s_barrier();
    asm volatile("" ::: "memory");

    bf16x8 af[4], bfr[4];
    #pragma unroll
    for (int mt = 0; mt < 4; ++mt)
      af[mt] = *(const bf16x8*)&As[bi][(wr + mt * 16 + l15) * 32 + g * 8];
    #pragma unroll
    for (int nt2 = 0; nt2 < 4; ++nt2)
      bfr[nt2] = *(const bf16x8*)&Bs[bi][(wc + nt2 * 16 + l15) * 32 + g * 8];
    #pragma unroll
    for (int mt = 0; mt < 4; ++mt)
      #pragma unroll
      for (int nt2 = 0; nt2 < 4; ++nt2)
        acc[mt][nt2] = __builtin_amdgcn_mfma_f32_16x16x32_bf16(af[mt], bfr[nt2], acc[mt][nt2], 0, 0, 0);

    asm volatile("" ::: "memory");
    __builtin_amdgcn_s_barrier();       // all reads of buf bi done
    bi ^= 1;
  }
#undef GSTAGE

  #pragma unroll
  for (int mt = 0; mt < 4; ++mt)
    #pragma unroll
    for (int r4 = 0; r4 < 4; ++r4) {
      const size_t row = (size_t)(m0 + wr + mt * 16 + 4 * g + r4);
      #pragma unroll
      for (int nt2 = 0; nt2 < 4; ++nt2)
        C[row * Nn + n0 + wc + nt2 * 16 + l15] = acc[mt][nt2][r4];
    }
}

// ---------------------------------------------------------------------------
__global__ void conv_x_kernel(const float* __restrict__ x, bf16* __restrict__ xb)
{
  int i = (blockIdx.x * 256 + threadIdx.x) * 8;
  float4 a = *(const float4*)&x[i];
  float4 b = *(const float4*)&x[i + 4];
  unsigned short* o = (unsigned short*)xb + i;
  *(ushort4*)o = make_ushort4(f2bf(a.x), f2bf(a.y), f2bf(a.z), f2bf(a.w));
  *(ushort4*)(o + 4) = make_ushort4(f2bf(b.x), f2bf(b.y), f2bf(b.z), f2bf(b.w));
}

// W[K][N] f32 -> Wt[N][K] bf16 (LDS-tiled 64x64 transpose + convert).
__global__ __launch_bounds__(256) void transpose_conv_kernel(
    const float* __restrict__ W, bf16* __restrict__ Wt, int Kk, int Nn)
{
  __shared__ float T[64][65];
  const int k0 = blockIdx.x * 64;
  const int n0 = blockIdx.y * 64;
  const int tid = threadIdx.x;
  const int lr = tid >> 4;
  const int lc = (tid & 15) * 4;
  #pragma unroll
  for (int i = 0; i < 4; ++i) {
    float4 v = *(const float4*)&W[(size_t)(k0 + lr + i * 16) * Nn + n0 + lc];
    T[lr + i * 16][lc + 0] = v.x;
    T[lr + i * 16][lc + 1] = v.y;
    T[lr + i * 16][lc + 2] = v.z;
    T[lr + i * 16][lc + 3] = v.w;
  }
  __syncthreads();
  const int rn = tid >> 3;
  const int ck = (tid & 7) * 8;
  #pragma unroll
  for (int i = 0; i < 2; ++i) {
    int nn = rn + i * 32;
    unsigned short u[8];
    #pragma unroll
    for (int e = 0; e < 8; ++e) u[e] = f2bf(T[ck + e][nn]);
    unsigned short* dst = (unsigned short*)Wt + (size_t)(n0 + nn) * Kk + k0 + ck;
    *(ushort4*)dst = make_ushort4(u[0], u[1], u[2], u[3]);
    *(ushort4*)(dst + 4) = make_ushort4(u[4], u[5], u[6], u[7]);
  }
}

// ---------------------------------------------------------------------------
// RoPE q from fused qkv buffer: qkv_f [B*S][1536], q at cols 0..1023.
// -> bf16 [B,H,S,HD]
__global__ void rope_q_kernel(const float* __restrict__ qf,
                              const float* __restrict__ fc,
                              const float* __restrict__ fs,
                              bf16* __restrict__ qb)
{
  int p = blockIdx.x * blockDim.x + threadIdx.x;
  int j = p & 31;
  int h = (p >> 5) & 15;
  int s = (p >> 9) & 2047;
  int b = p >> 20;
  const float* src = qf + (size_t)(b * CS + s) * 1536 + h * CHD + j * 2;
  float x0 = src[0], x1 = src[1];
  float c = fc[s * 32 + j], sn = fs[s * 32 + j];
  bf16* dst = qb + ((size_t)(b * CH + h) * CS + s) * CHD + j * 2;
  dst[0] = __float2bfloat16(x0 * c - x1 * sn);
  dst[1] = __float2bfloat16(x0 * sn + x1 * c);
}

// RoPE k from fused qkv buffer: k at cols 1024..1279.
__global__ void rope_k_kernel(const float* __restrict__ kvf,
                              const float* __restrict__ fc,
                              const float* __restrict__ fs,
                              bf16* __restrict__ kb)
{
  int p = blockIdx.x * blockDim.x + threadIdx.x;
  int j = p & 31;
  int kh = (p >> 5) & 3;
  int s = (p >> 7) & 2047;
  int b = p >> 18;
  const float* src = kvf + (size_t)(b * CS + s) * 1536 + 1024 + kh * CHD + j * 2;
  float x0 = src[0], x1 = src[1];
  float c = fc[s * 32 + j], sn = fs[s * 32 + j];
  bf16* dst = kb + ((size_t)(b * CKH + kh) * CS + s) * CHD + j * 2;
  dst[0] = __float2bfloat16(x0 * c - x1 * sn);
  dst[1] = __float2bfloat16(x0 * sn + x1 * c);
}

// V transpose: qkv_f [B*S][1536] (v at cols 1280..1535) -> vt [B,KH,HD,S] bf16.
__global__ __launch_bounds__(256) void transpose_v_kernel(
    const float* __restrict__ kvf, bf16* __restrict__ vt)
{
  __shared__ float T[64][65];
  const int blk = blockIdx.x;
  const int st = blk & 31;
  const int kh = (blk >> 5) & 3;
  const int b = blk >> 7;
  const int tid = threadIdx.x;
  const int s = tid >> 2;
  const int d0 = (tid & 3) * 16;
  const float* src = kvf + ((size_t)(b * CS + st * 64 + s)) * 1536 + 1280 + kh * CHD + d0;
  #pragma unroll
  for (int i = 0; i < 4; ++i) {
    float4 v = *(const float4*)(src + i * 4);
    T[s][d0 + i * 4 + 0] = v.x;
    T[s][d0 + i * 4 + 1] = v.y;
    T[s][d0 + i * 4 + 2] = v.z;
    T[s][d0 + i * 4 + 3] = v.w;
  }
  __syncthreads();
  const int d = tid >> 2;
  const int s0 = (tid & 3) * 16;
  unsigned short* dst = (unsigned short*)vt +
      ((size_t)((b * CKH + kh) * CHD + d)) * CS + st * 64 + s0;
  #pragma unroll
  for (int i = 0; i < 2; ++i) {
    unsigned short u[8];
    #pragma unroll
    for (int e = 0; e < 8; ++e) u[e] = f2bf(T[s0 + i * 8 + e][d]);
    *(ushort4*)(dst + i * 8 + 0) = make_ushort4(u[0], u[1], u[2], u[3]);
    *(ushort4*)(dst + i * 8 + 4) = make_ushort4(u[4], u[5], u[6], u[7]);
  }
}

// ---------------------------------------------------------------------------
// MFMA flash attention: EXACT R6 kernel (proven). Block = 4 waves = 4 q-heads
// of one kv group, one 32-row q-tile, KVBLK=64, dbuf LDS staging with counted
// vmcnt; XOR chunk swizzle; per-wave P via LDS; defer-max softmax.
// ---------------------------------------------------------------------------
__global__ __launch_bounds__(256, 2) void flash_mfma_kernel(
    const bf16* __restrict__ qb, const bf16* __restrict__ kb,
    const bf16* __restrict__ vt, bf16* __restrict__ ob)
{
  __shared__ __align__(16) char arena[51200];
  char* KL = arena;                       // [2][8192]: K tile 64x(64 bf16)
  char* VL = arena + 16384;               // [2][8192]: V^T tile 64x(64 bf16)
  const int tid = threadIdx.x;
  const int lane = tid & 63;
  const int wid = tid >> 6;
  unsigned short* PLW = (unsigned short*)(arena + 32768) + wid * 2304; // [32][72]
  const int l15 = lane & 15;
  const int g = lane >> 4;
  const int blk = blockIdx.x;
  const int grp = blk & 7;                // b*4+kh
  const int qt = 63 - (blk >> 3);         // LPT
  const int kh = grp & 3;
  const int b = grp >> 2;
  const int h = kh * CREP + wid;
  const int N64 = (qt >> 1) + 1;
  const float SC = 0.18033688f;           // 0.125 * log2(e)

  const bf16* qbase = qb + ((size_t)(b * CH + h) * CS + qt * 32) * CHD;
  const bf16* kbase = kb + (size_t)(b * CKH + kh) * CS * CHD;
  const bf16* vbase = vt + (size_t)(b * CKH + kh) * CHD * CS;  // [d][s]

  bf16x8 qf[2][2];
  #pragma unroll
  for (int qs = 0; qs < 2; ++qs)
    #pragma unroll
    for (int c = 0; c < 2; ++c)
      qf[qs][c] = *(const bf16x8*)(qbase + (qs * 16 + l15) * CHD + c * 32 + g * 8);

  bf16x8 ones;
  #pragma unroll
  for (int e = 0; e < 8; ++e) ones[e] = (short)0x3F80;  // bf16 1.0

  f32x4 oacc[2][4];
  f32x4 lacc[2];
  #pragma unroll
  for (int qs = 0; qs < 2; ++qs) {
    lacc[qs] = (f32x4){0.f, 0.f, 0.f, 0.f};
    #pragma unroll
    for (int dt = 0; dt < 4; ++dt)
      oacc[qs][dt] = (f32x4){0.f, 0.f, 0.f, 0.f};
  }
  float mrow[2] = {-1e30f, -1e30f};

  const int slr = tid >> 3;
  const int scg = (tid & 7) ^ (slr & 7);
  const bf16* kstage = kbase + (size_t)slr * CHD + scg * 8;
  const bf16* vstage = vbase + (size_t)slr * CS + scg * 8;
  char* kdst = KL + wid * 1024;
  char* vdst = VL + wid * 1024;

#define STAGE(bi, t64) do {                                        \
    const bf16* ks_ = kstage + (size_t)(t64) * 64 * CHD;           \
    const bf16* vs_ = vstage + (t64) * 64;                         \
    gload_lds16(ks_,            kdst + (bi) * 8192);               \
    gload_lds16(ks_ + 32 * CHD, kdst + (bi) * 8192 + 4096);        \
    gload_lds16(vs_,            vdst + (bi) * 8192);               \
    gload_lds16(vs_ + 32 * CS,  vdst + (bi) * 8192 + 4096);        \
  } while (0)

  int bi = 0;
  STAGE(0, 0);
  for (int t = 0; t < N64; ++t) {
    if (t + 1 < N64) {
      STAGE(bi ^ 1, t + 1);
      asm volatile("s_waitcnt vmcnt(4)" ::: "memory");
    } else {
      asm volatile("s_waitcnt vmcnt(0)" ::: "memory");
    }
    __builtin_amdgcn_s_barrier();
    asm volatile("" ::: "memory");

    const char* KB = KL + bi * 8192;
    const char* VB = VL + bi * 8192;
    bf16x8 kfr[4][2], vfr[4][2];
    #pragma unroll
    for (int kt = 0; kt < 4; ++kt) {
      int row = kt * 16 + l15;
      #pragma unroll
      for (int c = 0; c < 2; ++c)
        kfr[kt][c] = *(const bf16x8*)(KB + row * 128 + (((c * 4 + g) ^ (row & 7)) << 4));
    }
    #pragma unroll
    for (int dt = 0; dt < 4; ++dt) {
      int row = dt * 16 + l15;
      #pragma unroll
      for (int st = 0; st < 2; ++st)
        vfr[dt][st] = *(const bf16x8*)(VB + row * 128 + (((st * 4 + g) ^ (row & 7)) << 4));
    }

    // QK^T (swapped): S^T[k][q]
    f32x4 sacc[4][2];
    #pragma unroll
    for (int kt = 0; kt < 4; ++kt)
      #pragma unroll
      for (int qs = 0; qs < 2; ++qs)
        sacc[kt][qs] = (f32x4){0.f, 0.f, 0.f, 0.f};
    #pragma unroll
    for (int c = 0; c < 2; ++c)
      #pragma unroll
      for (int kt = 0; kt < 4; ++kt)
        #pragma unroll
        for (int qs = 0; qs < 2; ++qs)
          sacc[kt][qs] = __builtin_amdgcn_mfma_f32_16x16x32_bf16(kfr[kt][c], qf[qs][c], sacc[kt][qs], 0, 0, 0);

    const bool diag = (t == N64 - 1);
    #pragma unroll
    for (int qs = 0; qs < 2; ++qs) {
      float e[16];
      float pm = -1e30f;
      #pragma unroll
      for (int kt = 0; kt < 4; ++kt)
        #pragma unroll
        for (int r = 0; r < 4; ++r) {
          float v = sacc[kt][qs][r] * SC;
          if (diag) {
            int koff = t * 64 + kt * 16 + 4 * g + r;
            if (koff > qt * 32 + qs * 16 + l15) v = -1e30f;
          }
          e[kt * 4 + r] = v;
          pm = fmaxf(pm, v);
        }
      if (__any(pm > mrow[qs] + 8.0f)) {       // slow path: exact rescale
        pm = fmaxf(pm, __shfl_xor(pm, 16, 64));
        pm = fmaxf(pm, __shfl_xor(pm, 32, 64));
        float nm = fmaxf(mrow[qs], pm);
        float corr = exp2f(mrow[qs] - nm);
        mrow[qs] = nm;
        lacc[qs] *= corr;
        #pragma unroll
        for (int dt = 0; dt < 4; ++dt) oacc[qs][dt] *= corr;
      }
      unsigned short pb[16];
      #pragma unroll
      for (int i = 0; i < 16; ++i)
        pb[i] = f2bf(exp2f(e[i] - mrow[qs]));  // p <= 2^8
      #pragma unroll
      for (int kt = 0; kt < 4; ++kt)
        *(ushort4*)&PLW[(qs * 16 + l15) * 72 + kt * 16 + 4 * g] =
            make_ushort4(pb[kt * 4 + 0], pb[kt * 4 + 1], pb[kt * 4 + 2], pb[kt * 4 + 3]);
    }

    // PV + psum (same-wave LDS RAW)
    #pragma unroll
    for (int qs = 0; qs < 2; ++qs) {
      #pragma unroll
      for (int st = 0; st < 2; ++st) {
        bf16x8 pf = *(const bf16x8*)&PLW[(qs * 16 + l15) * 72 + st * 32 + g * 8];
        lacc[qs] = __builtin_amdgcn_mfma_f32_16x16x32_bf16(ones, pf, lacc[qs], 0, 0, 0);
        #pragma unroll
        for (int dt = 0; dt < 4; ++dt)
          oacc[qs][dt] = __builtin_amdgcn_mfma_f32_16x16x32_bf16(vfr[dt][st], pf, oacc[qs][dt], 0, 0, 0);
      }
    }

    asm volatile("" ::: "memory");
    __builtin_amdgcn_s_barrier();
    bi ^= 1;
  }
#undef STAGE

  #pragma unroll
  for (int qs = 0; qs < 2; ++qs) {
    float inv = 1.0f / lacc[qs][0];
    int qg = qt * 32 + qs * 16 + l15;
    unsigned short* orow = (unsigned short*)ob + (size_t)(b * CS + qg) * CNQ + h * CHD;
    #pragma unroll
    for (int dt = 0; dt < 4; ++dt) {
      *(ushort4*)&orow[dt * 16 + 4 * g] =
          make_ushort4(f2bf(oacc[qs][dt][0] * inv), f2bf(oacc[qs][dt][1] * inv),
                       f2bf(oacc[qs][dt][2] * inv), f2bf(oacc[qs][dt][3] * inv));
    }
  }
}

// ---------------------------------------------------------------------------
extern "C" void kernel_launch(void* const* d_in, const int* in_sizes, int n_in,
                              void* d_out, int out_size, void* d_ws, size_t ws_size,
                              hipStream_t stream)
{
  const float* x  = (const float*)d_in[0];
  const float* wq = (const float*)d_in[1];
  const float* wk = (const float*)d_in[2];
  const float* wv = (const float*)d_in[3];
  const float* wo = (const float*)d_in[4];
  const float* fc = (const float*)d_in[5];
  const float* fs = (const float*)d_in[6];
  float* out = (float*)d_out;

  char* ws = (char*)d_ws;
  // workspace (peak 37748736 B, same as proven R1 layout):
  //   x_b   [0, 8M)        bf16 4096x1024; dead after qkv GEMM
  //   qkv_f [8M, 33.5M)    f32 4096x1536;  dead after rope_q/rope_k/transpose_v
  //   wqkvt [33.5M, 36.7M) bf16 1536x1024; dead after qkv GEMM
  //   q_b   [0, 8M)        over x_b
  //   k_b   [33.5M, 35.5M) over wqkvt
  //   v_t   [35.5M, 37.75M... 35651584+2M) over wqkvt tail
  //   o_b   [8M, 16M)      over qkv_f
  //   wot   [16M, 18M)     over qkv_f (written after last qkv_f reader)
  bf16*  x_b   = (bf16*)(ws);
  float* qkv_f = (float*)(ws + 8388608);
  bf16*  wqkvt = (bf16*)(ws + 33554432);
  bf16*  q_b   = (bf16*)(ws);
  bf16*  k_b   = (bf16*)(ws + 33554432);
  bf16*  v_t   = (bf16*)(ws + 35651584);
  bf16*  o_b   = (bf16*)(ws + 8388608);
  bf16*  wot   = (bf16*)(ws + 16777216);

  conv_x_kernel<<<2048, 256, 0, stream>>>(x, x_b);
  transpose_conv_kernel<<<dim3(16, 16), 256, 0, stream>>>(wq, wqkvt, CD, CNQ);
  transpose_conv_kernel<<<dim3(16, 4), 256, 0, stream>>>(wk, wqkvt + (size_t)1024 * CD, CD, CNKV);
  transpose_conv_kernel<<<dim3(16, 4), 256, 0, stream>>>(wv, wqkvt + (size_t)1280 * CD, CD, CNKV);
  gemm_mfma_kernel<<<dim3(32, 12), 256, 0, stream>>>(x_b, wqkvt, qkv_f, CM, 1536, CD, CD);
  rope_q_kernel<<<(CB * CS * CH * 32) / 256, 256, 0, stream>>>(qkv_f, fc, fs, q_b);
  rope_k_kernel<<<(CB * CS * CKH * 32) / 256, 256, 0, stream>>>(qkv_f, fc, fs, k_b);
  transpose_v_kernel<<<CB * CKH * 32, 256, 0, stream>>>(qkv_f, v_t);
  transpose_conv_kernel<<<dim3(16, 16), 256, 0, stream>>>(wo, wot, CNQ, CD);
  flash_mfma_kernel<<<512, 256, 0, stream>>>(q_b, k_b, v_t, o_b);
  gemm_mfma_kernel<<<dim3(32, 8), 256, 0, stream>>>(o_b, wot, out, CM, CD, CNQ, CNQ);
}